// Round 6
// baseline (282.901 us; speedup 1.0000x reference)
//
#include <hip/hip_runtime.h>
#include <hip/hip_bf16.h>

#define HID 128

static inline size_t align256(size_t x) { return (x + 255) & ~(size_t)255; }

__device__ __forceinline__ float bf2f(unsigned short h) {
    return __uint_as_float(((unsigned int)h) << 16);
}
__device__ __forceinline__ unsigned short f2bf(float f) {
    unsigned int u = __float_as_uint(f);
    unsigned int r = (u + 0x7fffu + ((u >> 16) & 1u)) >> 16;  // RNE
    return (unsigned short)r;
}
// decode packed bf16x2 (little-endian: low 16 bits = element 0)
__device__ __forceinline__ float2 bf2x2(unsigned int u) {
    return make_float2(__uint_as_float(u << 16), __uint_as_float(u & 0xffff0000u));
}

// ---------------- degree count ----------------
__global__ void k_deg(const int* __restrict__ dst, int E, int* __restrict__ deg) {
    int e = blockIdx.x * blockDim.x + threadIdx.x;
    if (e < E) atomicAdd(&deg[dst[e]], 1);
}

// ---------------- prefix scan (3-phase) ----------------
__global__ void k_scan_local(const int* __restrict__ deg, int N,
                             int* __restrict__ excl, int* __restrict__ bsum) {
    __shared__ int s[256];
    int tid = threadIdx.x;
    int i = blockIdx.x * 256 + tid;
    int v = (i < N) ? deg[i] : 0;
    s[tid] = v;
    __syncthreads();
    for (int off = 1; off < 256; off <<= 1) {
        int t = (tid >= off) ? s[tid - off] : 0;
        __syncthreads();
        s[tid] += t;
        __syncthreads();
    }
    if (i < N) excl[i] = s[tid] - v;
    if (tid == 255) bsum[blockIdx.x] = s[255];
}

__global__ void k_scan_bsum(int* __restrict__ bsum, int NB) {
    __shared__ int s[256];
    int tid = threadIdx.x;
    int v = (tid < NB) ? bsum[tid] : 0;
    s[tid] = v;
    __syncthreads();
    for (int off = 1; off < 256; off <<= 1) {
        int t = (tid >= off) ? s[tid - off] : 0;
        __syncthreads();
        s[tid] += t;
        __syncthreads();
    }
    if (tid < NB) bsum[tid] = s[tid] - v;  // exclusive
}

__global__ void k_finalize(const int* __restrict__ deg, int N,
                           int* __restrict__ row_start, const int* __restrict__ bsum_ex,
                           int* __restrict__ cursor, float* __restrict__ dinv) {
    int i = blockIdx.x * blockDim.x + threadIdx.x;
    if (i < N) {
        int rs = row_start[i] + bsum_ex[blockIdx.x];
        row_start[i] = rs;
        cursor[i] = rs;
        dinv[i] = rsqrtf((float)(deg[i] + 1));  // +1 self loop
        if (i == N - 1) row_start[N] = rs + deg[i];
    }
}

// ---------------- edge bucket scatter ----------------
__global__ void k_scatter(const int* __restrict__ src, const int* __restrict__ dst, int E,
                          int* __restrict__ cursor, int* __restrict__ edge_src) {
    int e = blockIdx.x * blockDim.x + threadIdx.x;
    if (e < E) {
        int p = atomicAdd(&cursor[dst[e]], 1);
        edge_src[p] = src[e];
    }
}

// ---------------- GEMM1: hs = bf16((x @ W_gcn) * dinv[row]) ----------------
// x fp32 [N,128], W fp32 [128,128], hs bf16 [N,128]
__global__ __launch_bounds__(256) void k_gemm1(const float* __restrict__ x,
                                               const float* __restrict__ W,
                                               const float* __restrict__ dinv,
                                               unsigned short* __restrict__ hs, int N) {
    __shared__ float xsT[32][33];   // [k][row]
    __shared__ float Ws[32][128];   // [k][col]
    int tid = threadIdx.x;
    int cg = tid & 31;   // col quad: cols cg*4 .. cg*4+3
    int rg = tid >> 5;   // row group: rows rg*4 .. rg*4+3
    int row0 = blockIdx.x * 32;
    float acc[4][4] = {};
    for (int kk = 0; kk < HID; kk += 32) {
        {   // stage x tile: 32 rows x 32 k, transposed
            int r = tid >> 3, q = tid & 7;
            int row = row0 + r;
            float4 v = make_float4(0.f, 0.f, 0.f, 0.f);
            if (row < N) v = *(const float4*)(x + (size_t)row * HID + kk + q * 4);
            xsT[q * 4 + 0][r] = v.x;
            xsT[q * 4 + 1][r] = v.y;
            xsT[q * 4 + 2][r] = v.z;
            xsT[q * 4 + 3][r] = v.w;
        }
        {   // stage W tile: 32 k x 128 cols
            int cq = tid & 31, kr = tid >> 5;
#pragma unroll
            for (int k2 = kr; k2 < 32; k2 += 8) {
                float4 v = *(const float4*)(W + (size_t)(kk + k2) * HID + cq * 4);
                Ws[k2][cq * 4 + 0] = v.x;
                Ws[k2][cq * 4 + 1] = v.y;
                Ws[k2][cq * 4 + 2] = v.z;
                Ws[k2][cq * 4 + 3] = v.w;
            }
        }
        __syncthreads();
#pragma unroll
        for (int k = 0; k < 32; k++) {
            float a0 = xsT[k][rg * 4 + 0], a1 = xsT[k][rg * 4 + 1];
            float a2 = xsT[k][rg * 4 + 2], a3 = xsT[k][rg * 4 + 3];
            float b0 = Ws[k][cg * 4 + 0], b1 = Ws[k][cg * 4 + 1];
            float b2 = Ws[k][cg * 4 + 2], b3 = Ws[k][cg * 4 + 3];
            acc[0][0] += a0 * b0; acc[0][1] += a0 * b1; acc[0][2] += a0 * b2; acc[0][3] += a0 * b3;
            acc[1][0] += a1 * b0; acc[1][1] += a1 * b1; acc[1][2] += a1 * b2; acc[1][3] += a1 * b3;
            acc[2][0] += a2 * b0; acc[2][1] += a2 * b1; acc[2][2] += a2 * b2; acc[2][3] += a2 * b3;
            acc[3][0] += a3 * b0; acc[3][1] += a3 * b1; acc[3][2] += a3 * b2; acc[3][3] += a3 * b3;
        }
        __syncthreads();
    }
#pragma unroll
    for (int i = 0; i < 4; i++) {
        int row = row0 + rg * 4 + i;
        if (row < N) {
            float s = dinv[row];
            ushort4 v;
            v.x = f2bf(acc[i][0] * s);
            v.y = f2bf(acc[i][1] * s);
            v.z = f2bf(acc[i][2] * s);
            v.w = f2bf(acc[i][3] * s);
            *(ushort4*)(hs + (size_t)row * HID + cg * 4) = v;
        }
    }
}

// ---- propagate: out1 = bf16(relu(dinv[i]*(hs[i] + sum_edges hs[src]) + b_gcn)) ----
__global__ void k_prop(const unsigned short* __restrict__ hs, const int* __restrict__ row_start,
                       const int* __restrict__ edge_src, const float* __restrict__ dinv,
                       const float* __restrict__ b_gcn,
                       unsigned short* __restrict__ out1, int N) {
    int node = blockIdx.x * (blockDim.x >> 6) + (threadIdx.x >> 6);
    int lane = threadIdx.x & 63;
    if (node >= N) return;
    int s0 = row_start[node], s1 = row_start[node + 1];
    const unsigned int* hs32 = (const unsigned int*)hs;  // bf16x2 per uint
    float2 acc = bf2x2(hs32[(size_t)node * 64 + lane]);  // self loop
    int j = s0;
    for (; j + 1 < s1; j += 2) {
        int a = edge_src[j], b = edge_src[j + 1];
        float2 va = bf2x2(hs32[(size_t)a * 64 + lane]);
        float2 vb = bf2x2(hs32[(size_t)b * 64 + lane]);
        acc.x += va.x + vb.x;
        acc.y += va.y + vb.y;
    }
    if (j < s1) {
        float2 va = bf2x2(hs32[(size_t)edge_src[j] * 64 + lane]);
        acc.x += va.x;
        acc.y += va.y;
    }
    float di = dinv[node];
    float2 bb = *(const float2*)(b_gcn + lane * 2);
    float ox = fmaxf(di * acc.x + bb.x, 0.f);
    float oy = fmaxf(di * acc.y + bb.y, 0.f);
    unsigned int packed = (unsigned int)f2bf(ox) | ((unsigned int)f2bf(oy) << 16);
    ((unsigned int*)out1)[(size_t)node * 64 + lane] = packed;
}

// ---------------- MLP head: out = relu(out1@W1+b1) @ W2 + b2 (fused), fp32 out ----
__global__ __launch_bounds__(256) void k_mlp(const unsigned short* __restrict__ out1,
                                             const float* __restrict__ W1,
                                             const float* __restrict__ b1,
                                             const float* __restrict__ W2,
                                             const float* __restrict__ b2,
                                             float* __restrict__ out, int N) {
    __shared__ float xsT[32][33];
    __shared__ float Ws[32][128];
    __shared__ float sW2[128];
    __shared__ float sb1[128];
    int tid = threadIdx.x;
    if (tid < 128) { sW2[tid] = W2[tid]; sb1[tid] = b1[tid]; }
    int cg = tid & 31, rg = tid >> 5;
    int row0 = blockIdx.x * 32;
    float acc[4][4] = {};
    for (int kk = 0; kk < HID; kk += 32) {
        {   // stage out1 tile (bf16 -> fp32, transposed)
            int r = tid >> 3, q = tid & 7;
            int row = row0 + r;
            ushort4 v = make_ushort4(0, 0, 0, 0);
            if (row < N) v = *(const ushort4*)(out1 + (size_t)row * HID + kk + q * 4);
            xsT[q * 4 + 0][r] = bf2f(v.x);
            xsT[q * 4 + 1][r] = bf2f(v.y);
            xsT[q * 4 + 2][r] = bf2f(v.z);
            xsT[q * 4 + 3][r] = bf2f(v.w);
        }
        {   // stage W1 tile (fp32)
            int cq = tid & 31, kr = tid >> 5;
#pragma unroll
            for (int k2 = kr; k2 < 32; k2 += 8) {
                float4 v = *(const float4*)(W1 + (size_t)(kk + k2) * HID + cq * 4);
                Ws[k2][cq * 4 + 0] = v.x;
                Ws[k2][cq * 4 + 1] = v.y;
                Ws[k2][cq * 4 + 2] = v.z;
                Ws[k2][cq * 4 + 3] = v.w;
            }
        }
        __syncthreads();
#pragma unroll
        for (int k = 0; k < 32; k++) {
            float a0 = xsT[k][rg * 4 + 0], a1 = xsT[k][rg * 4 + 1];
            float a2 = xsT[k][rg * 4 + 2], a3 = xsT[k][rg * 4 + 3];
            float b0 = Ws[k][cg * 4 + 0], b1v = Ws[k][cg * 4 + 1];
            float b2v = Ws[k][cg * 4 + 2], b3 = Ws[k][cg * 4 + 3];
            acc[0][0] += a0 * b0; acc[0][1] += a0 * b1v; acc[0][2] += a0 * b2v; acc[0][3] += a0 * b3;
            acc[1][0] += a1 * b0; acc[1][1] += a1 * b1v; acc[1][2] += a1 * b2v; acc[1][3] += a1 * b3;
            acc[2][0] += a2 * b0; acc[2][1] += a2 * b1v; acc[2][2] += a2 * b2v; acc[2][3] += a2 * b3;
            acc[3][0] += a3 * b0; acc[3][1] += a3 * b1v; acc[3][2] += a3 * b2v; acc[3][3] += a3 * b3;
        }
        __syncthreads();
    }
    // epilogue: h2 = relu(acc + b1); partial = sum_j h2[c2]*W2[c2]
    float part[4];
#pragma unroll
    for (int i = 0; i < 4; i++) {
        float p = 0.f;
#pragma unroll
        for (int jj = 0; jj < 4; jj++) {
            int c2 = cg * 4 + jj;
            float h = fmaxf(acc[i][jj] + sb1[c2], 0.f);
            p += h * sW2[c2];
        }
        part[i] = p;
    }
#pragma unroll
    for (int off = 16; off >= 1; off >>= 1) {
#pragma unroll
        for (int i = 0; i < 4; i++) part[i] += __shfl_xor(part[i], off);
    }
    if (cg == 0) {
        float bb = b2[0];
#pragma unroll
        for (int i = 0; i < 4; i++) {
            int row = row0 + rg * 4 + i;
            if (row < N) out[row] = part[i] + bb;
        }
    }
}

extern "C" void kernel_launch(void* const* d_in, const int* in_sizes, int n_in,
                              void* d_out, int out_size, void* d_ws, size_t ws_size,
                              hipStream_t stream) {
    const float* x     = (const float*)d_in[0];
    const int*   ei    = (const int*)d_in[1];
    const float* W_gcn = (const float*)d_in[2];
    const float* b_gcn = (const float*)d_in[3];
    const float* W1    = (const float*)d_in[4];
    const float* b1    = (const float*)d_in[5];
    const float* W2    = (const float*)d_in[6];
    const float* b2    = (const float*)d_in[7];
    float* out = (float*)d_out;  // reference output dtype is fp32

    int N = in_sizes[0] / HID;
    int E = in_sizes[1] / 2;
    const int* e_src = ei;
    const int* e_dst = ei + E;

    // workspace carve-up (~30 MB total)
    char* ws = (char*)d_ws;
    size_t off = 0;
    unsigned short* hs = (unsigned short*)(ws + off);   off = align256(off + (size_t)N * HID * 2);
    unsigned short* out1 = (unsigned short*)(ws + off); off = align256(off + (size_t)N * HID * 2);
    float* dinv = (float*)(ws + off);                   off = align256(off + (size_t)N * 4);
    int* deg = (int*)(ws + off);                        off = align256(off + (size_t)N * 4);
    int* row_start = (int*)(ws + off);                  off = align256(off + (size_t)(N + 1) * 4);
    int* cursor = (int*)(ws + off);                     off = align256(off + (size_t)N * 4);
    int* edge_src = (int*)(ws + off);                   off = align256(off + (size_t)E * 4);
    int* bsum = (int*)(ws + off);                       off = align256(off + 1024);

    int NB = (N + 255) / 256;

    hipMemsetAsync(deg, 0, (size_t)N * 4, stream);
    k_deg<<<(E + 255) / 256, 256, 0, stream>>>(e_dst, E, deg);
    k_scan_local<<<NB, 256, 0, stream>>>(deg, N, row_start, bsum);
    k_scan_bsum<<<1, 256, 0, stream>>>(bsum, NB);
    k_finalize<<<NB, 256, 0, stream>>>(deg, N, row_start, bsum, cursor, dinv);
    k_scatter<<<(E + 255) / 256, 256, 0, stream>>>(e_src, e_dst, E, cursor, edge_src);

    int gemm_blocks = (N + 31) / 32;
    k_gemm1<<<gemm_blocks, 256, 0, stream>>>(x, W_gcn, dinv, hs, N);

    int prop_blocks = (N + 3) / 4;  // 4 nodes per 256-thread block
    k_prop<<<prop_blocks, 256, 0, stream>>>(hs, row_start, edge_src, dinv, b_gcn, out1, N);

    k_mlp<<<gemm_blocks, 256, 0, stream>>>(out1, W1, b1, W2, b2, out, N);
}

// Round 7
// 261.262 us; speedup vs baseline: 1.0828x; 1.0828x over previous
//
#include <hip/hip_runtime.h>
#include <hip/hip_bf16.h>

#define HID 128

typedef __attribute__((ext_vector_type(8))) short bf16x8;
typedef __attribute__((ext_vector_type(4))) float f32x4;

static inline size_t align256(size_t x) { return (x + 255) & ~(size_t)255; }

__device__ __forceinline__ float bf2f(unsigned short h) {
    return __uint_as_float(((unsigned int)h) << 16);
}
__device__ __forceinline__ unsigned short f2bf(float f) {
    unsigned int u = __float_as_uint(f);
    unsigned int r = (u + 0x7fffu + ((u >> 16) & 1u)) >> 16;  // RNE
    return (unsigned short)r;
}
__device__ __forceinline__ float2 bf2x2(unsigned int u) {
    return make_float2(__uint_as_float(u << 16), __uint_as_float(u & 0xffff0000u));
}

// ---------------- prep: transpose W_gcn, W1 to bf16 n-major [n][k] ----------------
__global__ void k_prep(const float* __restrict__ W, const float* __restrict__ W1,
                       unsigned short* __restrict__ WT, unsigned short* __restrict__ W1T) {
    int idx = blockIdx.x * 256 + threadIdx.x;  // 0..16383
    if (idx < HID * HID) {
        int k = idx >> 7, n = idx & 127;
        WT[n * HID + k]  = f2bf(W[idx]);    // W[k][n] -> WT[n][k]
        W1T[n * HID + k] = f2bf(W1[idx]);
    }
}

// ---------------- degree count ----------------
__global__ void k_deg(const int* __restrict__ dst, int E, int* __restrict__ deg) {
    int e = blockIdx.x * blockDim.x + threadIdx.x;
    if (e < E) atomicAdd(&deg[dst[e]], 1);
}

// ---------------- prefix scan (3-phase) ----------------
__global__ void k_scan_local(const int* __restrict__ deg, int N,
                             int* __restrict__ excl, int* __restrict__ bsum) {
    __shared__ int s[256];
    int tid = threadIdx.x;
    int i = blockIdx.x * 256 + tid;
    int v = (i < N) ? deg[i] : 0;
    s[tid] = v;
    __syncthreads();
    for (int off = 1; off < 256; off <<= 1) {
        int t = (tid >= off) ? s[tid - off] : 0;
        __syncthreads();
        s[tid] += t;
        __syncthreads();
    }
    if (i < N) excl[i] = s[tid] - v;
    if (tid == 255) bsum[blockIdx.x] = s[255];
}

__global__ void k_scan_bsum(int* __restrict__ bsum, int NB) {
    __shared__ int s[256];
    int tid = threadIdx.x;
    int v = (tid < NB) ? bsum[tid] : 0;
    s[tid] = v;
    __syncthreads();
    for (int off = 1; off < 256; off <<= 1) {
        int t = (tid >= off) ? s[tid - off] : 0;
        __syncthreads();
        s[tid] += t;
        __syncthreads();
    }
    if (tid < NB) bsum[tid] = s[tid] - v;  // exclusive
}

__global__ void k_finalize(const int* __restrict__ deg, int N,
                           int* __restrict__ row_start, const int* __restrict__ bsum_ex,
                           int* __restrict__ cursor, float* __restrict__ dinv) {
    int i = blockIdx.x * blockDim.x + threadIdx.x;
    if (i < N) {
        int rs = row_start[i] + bsum_ex[blockIdx.x];
        row_start[i] = rs;
        cursor[i] = rs;
        dinv[i] = rsqrtf((float)(deg[i] + 1));  // +1 self loop
        if (i == N - 1) row_start[N] = rs + deg[i];
    }
}

// ---------------- edge bucket scatter ----------------
__global__ void k_scatter(const int* __restrict__ src, const int* __restrict__ dst, int E,
                          int* __restrict__ cursor, int* __restrict__ edge_src) {
    int e = blockIdx.x * blockDim.x + threadIdx.x;
    if (e < E) {
        int p = atomicAdd(&cursor[dst[e]], 1);
        edge_src[p] = src[e];
    }
}

// ---------------- GEMM1 (MFMA): hs = bf16((x @ W_gcn) * dinv[row]) ----------------
// A = x fp32 [N,128] (cast to bf16 in-flight); B = WT bf16 [n][k]; 64 rows/block.
__global__ __launch_bounds__(256) void k_gemm1(const float* __restrict__ x,
                                               const unsigned short* __restrict__ WT,
                                               const float* __restrict__ dinv,
                                               unsigned short* __restrict__ hs, int N) {
    int tid = threadIdx.x;
    int wid = tid >> 6, lane = tid & 63;
    int m = lane & 15;     // A row within wave tile / B col within n-tile
    int q = lane >> 4;     // quad -> k-slice q*8..q*8+7
    int row0 = blockIdx.x * 64 + wid * 16;
    int arow_i = row0 + m;
    bool rvalid = arow_i < N;
    const float* arow = x + (size_t)arow_i * HID;
    f32x4 acc[8];
#pragma unroll
    for (int t = 0; t < 8; t++) acc[t] = (f32x4){0.f, 0.f, 0.f, 0.f};
#pragma unroll
    for (int c = 0; c < 4; c++) {
        bf16x8 a;
        if (rvalid) {
            float4 f0 = *(const float4*)(arow + c * 32 + q * 8);
            float4 f1 = *(const float4*)(arow + c * 32 + q * 8 + 4);
            a = (bf16x8){(short)f2bf(f0.x), (short)f2bf(f0.y), (short)f2bf(f0.z), (short)f2bf(f0.w),
                         (short)f2bf(f1.x), (short)f2bf(f1.y), (short)f2bf(f1.z), (short)f2bf(f1.w)};
        } else {
            a = (bf16x8){0, 0, 0, 0, 0, 0, 0, 0};
        }
#pragma unroll
        for (int t = 0; t < 8; t++) {
            bf16x8 b = *(const bf16x8*)(WT + (size_t)(t * 16 + m) * HID + c * 32 + q * 8);
            acc[t] = __builtin_amdgcn_mfma_f32_16x16x32_bf16(a, b, acc[t], 0, 0, 0);
        }
    }
    // C/D layout: col = t*16 + m, row = row0 + q*4 + r
    float dv[4];
#pragma unroll
    for (int r = 0; r < 4; r++) {
        int rr = row0 + q * 4 + r;
        dv[r] = (rr < N) ? dinv[rr] : 0.f;
    }
#pragma unroll
    for (int t = 0; t < 8; t++) {
#pragma unroll
        for (int r = 0; r < 4; r++) {
            int rr = row0 + q * 4 + r;
            if (rr < N) hs[(size_t)rr * HID + t * 16 + m] = f2bf(acc[t][r] * dv[r]);
        }
    }
}

// ---- propagate: out1 = bf16(relu(dinv[i]*(hs[i] + sum_edges hs[src]) + b_gcn)) ----
__global__ void k_prop(const unsigned short* __restrict__ hs, const int* __restrict__ row_start,
                       const int* __restrict__ edge_src, const float* __restrict__ dinv,
                       const float* __restrict__ b_gcn,
                       unsigned short* __restrict__ out1, int N) {
    int node = blockIdx.x * (blockDim.x >> 6) + (threadIdx.x >> 6);
    int lane = threadIdx.x & 63;
    if (node >= N) return;
    int s0 = row_start[node], s1 = row_start[node + 1];
    const unsigned int* hs32 = (const unsigned int*)hs;  // bf16x2 per uint
    float2 acc = bf2x2(hs32[(size_t)node * 64 + lane]);  // self loop
    int j = s0;
    for (; j + 4 <= s1; j += 4) {  // 4 outstanding gathers
        int i0 = edge_src[j], i1 = edge_src[j + 1], i2 = edge_src[j + 2], i3 = edge_src[j + 3];
        unsigned int u0 = hs32[(size_t)i0 * 64 + lane];
        unsigned int u1 = hs32[(size_t)i1 * 64 + lane];
        unsigned int u2 = hs32[(size_t)i2 * 64 + lane];
        unsigned int u3 = hs32[(size_t)i3 * 64 + lane];
        float2 v0 = bf2x2(u0), v1 = bf2x2(u1), v2 = bf2x2(u2), v3 = bf2x2(u3);
        acc.x += (v0.x + v1.x) + (v2.x + v3.x);
        acc.y += (v0.y + v1.y) + (v2.y + v3.y);
    }
    for (; j < s1; j++) {
        float2 va = bf2x2(hs32[(size_t)edge_src[j] * 64 + lane]);
        acc.x += va.x;
        acc.y += va.y;
    }
    float di = dinv[node];
    float2 bb = *(const float2*)(b_gcn + lane * 2);
    float ox = fmaxf(di * acc.x + bb.x, 0.f);
    float oy = fmaxf(di * acc.y + bb.y, 0.f);
    unsigned int packed = (unsigned int)f2bf(ox) | ((unsigned int)f2bf(oy) << 16);
    ((unsigned int*)out1)[(size_t)node * 64 + lane] = packed;
}

// ------- MLP head (MFMA): out = relu(out1@W1+b1) @ W2 + b2, fused epilogue -------
__global__ __launch_bounds__(256) void k_mlp(const unsigned short* __restrict__ out1,
                                             const unsigned short* __restrict__ W1T,
                                             const float* __restrict__ b1,
                                             const float* __restrict__ W2,
                                             const float* __restrict__ b2,
                                             float* __restrict__ out, int N) {
    __shared__ float sb1[128], sW2[128];
    int tid = threadIdx.x;
    if (tid < 128) { sb1[tid] = b1[tid]; sW2[tid] = W2[tid]; }
    __syncthreads();
    int wid = tid >> 6, lane = tid & 63;
    int m = lane & 15, q = lane >> 4;
    int row0 = blockIdx.x * 64 + wid * 16;
    int arow_i = row0 + m;
    bool rvalid = arow_i < N;
    const unsigned short* arow = out1 + (size_t)arow_i * HID;
    f32x4 acc[8];
#pragma unroll
    for (int t = 0; t < 8; t++) acc[t] = (f32x4){0.f, 0.f, 0.f, 0.f};
#pragma unroll
    for (int c = 0; c < 4; c++) {
        bf16x8 a = rvalid ? *(const bf16x8*)(arow + c * 32 + q * 8)
                          : (bf16x8){0, 0, 0, 0, 0, 0, 0, 0};
#pragma unroll
        for (int t = 0; t < 8; t++) {
            bf16x8 b = *(const bf16x8*)(W1T + (size_t)(t * 16 + m) * HID + c * 32 + q * 8);
            acc[t] = __builtin_amdgcn_mfma_f32_16x16x32_bf16(a, b, acc[t], 0, 0, 0);
        }
    }
    // epilogue: h2[row][col] = relu(acc + b1[col]); part[row] = sum_col h2*W2[col]
    float part[4] = {0.f, 0.f, 0.f, 0.f};
#pragma unroll
    for (int t = 0; t < 8; t++) {
        int nc = t * 16 + m;
        float w2 = sW2[nc], bb = sb1[nc];
#pragma unroll
        for (int r = 0; r < 4; r++)
            part[r] += fmaxf(acc[t][r] + bb, 0.f) * w2;
    }
    // reduce across the 16 m-lanes (xor stays within 16-aligned groups)
#pragma unroll
    for (int off = 8; off >= 1; off >>= 1) {
#pragma unroll
        for (int r = 0; r < 4; r++) part[r] += __shfl_xor(part[r], off);
    }
    if (m == 0) {
        float bb = b2[0];
#pragma unroll
        for (int r = 0; r < 4; r++) {
            int rr = row0 + q * 4 + r;
            if (rr < N) out[rr] = part[r] + bb;
        }
    }
}

extern "C" void kernel_launch(void* const* d_in, const int* in_sizes, int n_in,
                              void* d_out, int out_size, void* d_ws, size_t ws_size,
                              hipStream_t stream) {
    const float* x     = (const float*)d_in[0];
    const int*   ei    = (const int*)d_in[1];
    const float* W_gcn = (const float*)d_in[2];
    const float* b_gcn = (const float*)d_in[3];
    const float* W1    = (const float*)d_in[4];
    const float* b1    = (const float*)d_in[5];
    const float* W2    = (const float*)d_in[6];
    const float* b2    = (const float*)d_in[7];
    float* out = (float*)d_out;

    int N = in_sizes[0] / HID;
    int E = in_sizes[1] / 2;
    const int* e_src = ei;
    const int* e_dst = ei + E;

    // workspace carve-up (~30 MB total)
    char* ws = (char*)d_ws;
    size_t off = 0;
    unsigned short* hs = (unsigned short*)(ws + off);   off = align256(off + (size_t)N * HID * 2);
    unsigned short* out1 = (unsigned short*)(ws + off); off = align256(off + (size_t)N * HID * 2);
    float* dinv = (float*)(ws + off);                   off = align256(off + (size_t)N * 4);
    int* deg = (int*)(ws + off);                        off = align256(off + (size_t)N * 4);
    int* row_start = (int*)(ws + off);                  off = align256(off + (size_t)(N + 1) * 4);
    int* cursor = (int*)(ws + off);                     off = align256(off + (size_t)N * 4);
    int* edge_src = (int*)(ws + off);                   off = align256(off + (size_t)E * 4);
    int* bsum = (int*)(ws + off);                       off = align256(off + 1024);
    unsigned short* WT = (unsigned short*)(ws + off);   off = align256(off + (size_t)HID * HID * 2);
    unsigned short* W1T = (unsigned short*)(ws + off);  off = align256(off + (size_t)HID * HID * 2);

    int NB = (N + 255) / 256;

    k_prep<<<(HID * HID + 255) / 256, 256, 0, stream>>>(W_gcn, W1, WT, W1T);

    hipMemsetAsync(deg, 0, (size_t)N * 4, stream);
    k_deg<<<(E + 255) / 256, 256, 0, stream>>>(e_dst, E, deg);
    k_scan_local<<<NB, 256, 0, stream>>>(deg, N, row_start, bsum);
    k_scan_bsum<<<1, 256, 0, stream>>>(bsum, NB);
    k_finalize<<<NB, 256, 0, stream>>>(deg, N, row_start, bsum, cursor, dinv);
    k_scatter<<<(E + 255) / 256, 256, 0, stream>>>(e_src, e_dst, E, cursor, edge_src);

    int mfma_blocks = (N + 63) / 64;
    k_gemm1<<<mfma_blocks, 256, 0, stream>>>(x, WT, dinv, hs, N);

    int prop_blocks = (N + 3) / 4;  // 4 nodes per 256-thread block
    k_prop<<<prop_blocks, 256, 0, stream>>>(hs, row_start, edge_src, dinv, b_gcn, out1, N);

    k_mlp<<<mfma_blocks, 256, 0, stream>>>(out1, W1T, b1, W2, b2, out, N);
}